// Round 9
// baseline (5476.126 us; speedup 1.0000x reference)
//
#include <hip/hip_runtime.h>
#include <math.h>

// Problem constants (fixed by the reference)
#define BB   2
#define TT   2048
#define CC   256          // DIM = HD = HV = K = V = 256, H = 1
#define BT   (BB*TT)      // 4096 rows
#define BTC  ((size_t)BT*CC)   // 1,048,576 elements
#define LE   64           // expanded chunk length (32 timesteps x 2 heads)
#define LT   32           // timesteps per chunk
#define NCH  (TT/LT)      // 64 chunks per batch
#define TE   (2*TT)       // expanded sequence length
#define NCB  (BB*NCH)     // 128 chunk-blocks

// ---------------------------------------------------------------------------
// fp32 tiled GEMM: C[M,N] = A[M,K] @ B[K,N]
// ---------------------------------------------------------------------------
__global__ __launch_bounds__(256) void gemm_f32(
    const float* __restrict__ A, const float* __restrict__ B,
    float* __restrict__ C, int M, int N, int K)
{
    __shared__ float As[16][64];
    __shared__ float Bs[16][64];
    const int tid = threadIdx.x;
    const int tx = tid & 15;
    const int ty = tid >> 4;
    const int brow = blockIdx.x * 64;
    const int bcol = blockIdx.y * 64;

    const int ar = tid >> 2;
    const int ac = (tid & 3) * 4;
    const int bkr = tid >> 4;
    const int bc  = (tid & 15) * 4;

    float acc[4][4];
#pragma unroll
    for (int i = 0; i < 4; i++)
#pragma unroll
        for (int j = 0; j < 4; j++) acc[i][j] = 0.f;

    for (int kb = 0; kb < K; kb += 16) {
        float4 av = *(const float4*)(A + (size_t)(brow + ar) * K + kb + ac);
        As[ac + 0][ar] = av.x; As[ac + 1][ar] = av.y;
        As[ac + 2][ar] = av.z; As[ac + 3][ar] = av.w;
        float4 bv = *(const float4*)(B + (size_t)(kb + bkr) * N + bcol + bc);
        *(float4*)&Bs[bkr][bc] = bv;
        __syncthreads();
#pragma unroll
        for (int kk = 0; kk < 16; kk++) {
            float4 a4 = *(const float4*)&As[kk][ty * 4];
            float4 b4 = *(const float4*)&Bs[kk][tx * 4];
            float aa[4] = {a4.x, a4.y, a4.z, a4.w};
            float bb_[4] = {b4.x, b4.y, b4.z, b4.w};
#pragma unroll
            for (int i = 0; i < 4; i++)
#pragma unroll
                for (int j = 0; j < 4; j++) acc[i][j] += aa[i] * bb_[j];
        }
        __syncthreads();
    }
#pragma unroll
    for (int i = 0; i < 4; i++) {
        float4 o = make_float4(acc[i][0], acc[i][1], acc[i][2], acc[i][3]);
        *(float4*)(C + (size_t)(brow + ty * 4 + i) * N + bcol + tx * 4) = o;
    }
}

// Batched variant: 6 projections sharing A = x.
struct GemmBatch { const float* B[6]; float* C[6]; };
__global__ __launch_bounds__(256) void gemm_f32_batch(
    const float* __restrict__ A, GemmBatch p, int M, int N, int K)
{
    __shared__ float As[16][64];
    __shared__ float Bs[16][64];
    const float* __restrict__ B = p.B[blockIdx.z];
    float* __restrict__ C = p.C[blockIdx.z];
    const int tid = threadIdx.x;
    const int tx = tid & 15;
    const int ty = tid >> 4;
    const int brow = blockIdx.x * 64;
    const int bcol = blockIdx.y * 64;
    const int ar = tid >> 2;
    const int ac = (tid & 3) * 4;
    const int bkr = tid >> 4;
    const int bc  = (tid & 15) * 4;

    float acc[4][4];
#pragma unroll
    for (int i = 0; i < 4; i++)
#pragma unroll
        for (int j = 0; j < 4; j++) acc[i][j] = 0.f;

    for (int kb = 0; kb < K; kb += 16) {
        float4 av = *(const float4*)(A + (size_t)(brow + ar) * K + kb + ac);
        As[ac + 0][ar] = av.x; As[ac + 1][ar] = av.y;
        As[ac + 2][ar] = av.z; As[ac + 3][ar] = av.w;
        float4 bv = *(const float4*)(B + (size_t)(kb + bkr) * N + bcol + bc);
        *(float4*)&Bs[bkr][bc] = bv;
        __syncthreads();
#pragma unroll
        for (int kk = 0; kk < 16; kk++) {
            float4 a4 = *(const float4*)&As[kk][ty * 4];
            float4 b4 = *(const float4*)&Bs[kk][tx * 4];
            float aa[4] = {a4.x, a4.y, a4.z, a4.w};
            float bb_[4] = {b4.x, b4.y, b4.z, b4.w};
#pragma unroll
            for (int i = 0; i < 4; i++)
#pragma unroll
                for (int j = 0; j < 4; j++) acc[i][j] += aa[i] * bb_[j];
        }
        __syncthreads();
    }
#pragma unroll
    for (int i = 0; i < 4; i++) {
        float4 o = make_float4(acc[i][0], acc[i][1], acc[i][2], acc[i][3]);
        *(float4*)(C + (size_t)(brow + ty * 4 + i) * N + bcol + tx * 4) = o;
    }
}

// ---------------------------------------------------------------------------
// g / beta scalar projections.
// ---------------------------------------------------------------------------
__global__ __launch_bounds__(64) void proj_scalars(
    const float* __restrict__ x, const float* __restrict__ Wb,
    const float* __restrict__ Wa, const float* __restrict__ A_log,
    const float* __restrict__ dt_bias,
    float* __restrict__ g_arr, float* __restrict__ beta_arr)
{
    const int row = blockIdx.x;
    const int lane = threadIdx.x;
    float4 xv = ((const float4*)(x + (size_t)row * CC))[lane];
    float4 wa = ((const float4*)Wa)[lane];
    float4 w0 = ((const float4*)Wb)[lane];
    float4 w1 = ((const float4*)(Wb + CC))[lane];
    float da = xv.x * wa.x + xv.y * wa.y + xv.z * wa.z + xv.w * wa.w;
    float d0 = xv.x * w0.x + xv.y * w0.y + xv.z * w0.z + xv.w * w0.w;
    float d1 = xv.x * w1.x + xv.y * w1.y + xv.z * w1.z + xv.w * w1.w;
#pragma unroll
    for (int m = 1; m < 64; m <<= 1) {
        da += __shfl_xor(da, m, 64);
        d0 += __shfl_xor(d0, m, 64);
        d1 += __shfl_xor(d1, m, 64);
    }
    if (lane == 0) {
        float sp_in = da + dt_bias[0];
        float sp = (sp_in > 20.f) ? sp_in : log1pf(expf(sp_in));
        g_arr[row] = -expf(A_log[0]) * sp;
        beta_arr[row * 2 + 0] = 1.f / (1.f + expf(-d0));
        beta_arr[row * 2 + 1] = 1.f / (1.f + expf(-d1));
    }
}

// ---------------------------------------------------------------------------
// Causal conv (CONV=4) + silu + optional per-row l2norm.
// ---------------------------------------------------------------------------
__global__ __launch_bounds__(256) void conv_silu(
    const float* __restrict__ q_pre, const float* __restrict__ k_pre,
    const float* __restrict__ v_pre,
    const float* __restrict__ qw, const float* __restrict__ kw,
    const float* __restrict__ vw,
    float* __restrict__ qn, float* __restrict__ kn, float* __restrict__ vn)
{
    const int bt = blockIdx.x;
    const int s  = blockIdx.y;
    const int c  = threadIdx.x;
    const int t  = bt & (TT - 1);

    const float* pre; const float* w; float* out; bool donorm;
    if (s == 0)      { pre = q_pre;       w = qw;         out = qn + (size_t)bt * CC;            donorm = true;  }
    else if (s == 1) { pre = k_pre;       w = kw;         out = kn + ((size_t)bt * 2 + 0) * CC;  donorm = true;  }
    else if (s == 2) { pre = k_pre + BTC; w = kw + CC*4;  out = kn + ((size_t)bt * 2 + 1) * CC;  donorm = true;  }
    else if (s == 3) { pre = v_pre;       w = vw;         out = vn + ((size_t)bt * 2 + 0) * CC;  donorm = false; }
    else             { pre = v_pre + BTC; w = vw + CC*4;  out = vn + ((size_t)bt * 2 + 1) * CC;  donorm = false; }

    const float w0 = w[c * 4 + 0], w1 = w[c * 4 + 1], w2 = w[c * 4 + 2], w3 = w[c * 4 + 3];
    float acc = 0.f;
    if (t >= 3) acc += pre[(size_t)(bt - 3) * CC + c] * w0;
    if (t >= 2) acc += pre[(size_t)(bt - 2) * CC + c] * w1;
    if (t >= 1) acc += pre[(size_t)(bt - 1) * CC + c] * w2;
    acc += pre[(size_t)bt * CC + c] * w3;
    float val = acc / (1.f + expf(-acc));   // silu

    if (donorm) {
        float ss = val * val;
#pragma unroll
        for (int m = 1; m < 64; m <<= 1) ss += __shfl_xor(ss, m, 64);
        __shared__ float red[4];
        if ((c & 63) == 0) red[c >> 6] = ss;
        __syncthreads();
        float tot = red[0] + red[1] + red[2] + red[3];
        val *= rsqrtf(tot + 1e-6f);
    }
    out[c] = val;
}

// ---------------------------------------------------------------------------
// chunk_pre: A-matrix, forward substitution -> Wm, U_loc, Mq, meta
// ---------------------------------------------------------------------------
__global__ __launch_bounds__(256) void chunk_pre(
    const float* __restrict__ qn, const float* __restrict__ kn,
    const float* __restrict__ vn, const float* __restrict__ g_arr,
    const float* __restrict__ beta_arr,
    float* __restrict__ cWm, float* __restrict__ cUl,
    float* __restrict__ cMq, float* __restrict__ cMeta)
{
    extern __shared__ float sm[];
    float* Kl  = sm;              // [64][260]
    float* Al  = sm + 16640;      // [64][65]
    float* Cr  = sm + 20800;      // region C
    float* gcl = sm + 37440;
    float* bl  = sm + 37504;
    float* Dl  = sm + 37568;

    const int tid = threadIdx.x;
    const int ch = blockIdx.x, b = blockIdx.y;
    const size_t cb = (size_t)b * NCH + ch;
    const float* kg = kn + ((size_t)b * TE + (size_t)ch * LE) * CC;
    const float* vg = vn + ((size_t)b * TE + (size_t)ch * LE) * CC;
    const float* qg = qn + ((size_t)b * TT + (size_t)ch * LT) * CC;

    {
        const int r0 = (tid >> 6) * 16;
        const int k4 = (tid & 63) * 4;
#pragma unroll
        for (int m = 0; m < 16; m++) {
            float4 v = *(const float4*)(kg + (size_t)(r0 + m) * CC + k4);
            *(float4*)(Kl + (r0 + m) * 260 + k4) = v;
        }
    }
    if (tid < 64) {
        bl[tid] = beta_arr[(size_t)b * TE + (size_t)ch * LE + tid];
        Dl[tid] = (tid & 1) ? 0.f : g_arr[(size_t)b * TT + (size_t)ch * LT + (tid >> 1)];
    }
    __syncthreads();
    if (tid == 0) {
        float s = 0.f;
        for (int u = 0; u < 64; u++) { s += Dl[u]; gcl[u] = s; }
    }
    __syncthreads();
    if (tid < 64) Dl[tid] = expf(gcl[tid]);

    {
        const int ti = tid >> 4, tj = tid & 15;
        float4 acc[4][4];
#pragma unroll
        for (int a = 0; a < 4; a++)
#pragma unroll
            for (int c2 = 0; c2 < 4; c2++) acc[a][c2] = make_float4(0.f,0.f,0.f,0.f);
        for (int k4 = 0; k4 < 256; k4 += 4) {
            float4 av[4], bv[4];
#pragma unroll
            for (int m = 0; m < 4; m++) av[m] = *(const float4*)(Kl + (ti + 16*m)*260 + k4);
#pragma unroll
            for (int m = 0; m < 4; m++) bv[m] = *(const float4*)(Kl + (tj + 16*m)*260 + k4);
#pragma unroll
            for (int a = 0; a < 4; a++)
#pragma unroll
                for (int c2 = 0; c2 < 4; c2++) {
                    acc[a][c2].x += av[a].x * bv[c2].x;
                    acc[a][c2].y += av[a].y * bv[c2].y;
                    acc[a][c2].z += av[a].z * bv[c2].z;
                    acc[a][c2].w += av[a].w * bv[c2].w;
                }
        }
#pragma unroll
        for (int a = 0; a < 4; a++)
#pragma unroll
            for (int c2 = 0; c2 < 4; c2++) {
                int i = ti + 16*a, j = tj + 16*c2;
                float d = acc[a][c2].x + acc[a][c2].y + acc[a][c2].z + acc[a][c2].w;
                Al[i*65 + j] = (j < i) ? bl[i] * expf(gcl[i] - gcl[j]) * d : 0.f;
            }
    }
    {
        const int r0 = (tid >> 6) * 8;
        const int k4 = (tid & 63) * 4;
#pragma unroll
        for (int m = 0; m < 8; m++) {
            float4 v = *(const float4*)(qg + (size_t)(r0 + m) * CC + k4);
            *(float4*)(Cr + (r0 + m) * 260 + k4) = v;
        }
    }
    __syncthreads();
    {
        const int tr = tid >> 4, tj = tid & 15;
        float4 acc[2][4];
#pragma unroll
        for (int a = 0; a < 2; a++)
#pragma unroll
            for (int c2 = 0; c2 < 4; c2++) acc[a][c2] = make_float4(0.f,0.f,0.f,0.f);
        for (int k4 = 0; k4 < 256; k4 += 4) {
            float4 av[2], bv[4];
#pragma unroll
            for (int m = 0; m < 2; m++) av[m] = *(const float4*)(Cr + (tr + 16*m)*260 + k4);
#pragma unroll
            for (int m = 0; m < 4; m++) bv[m] = *(const float4*)(Kl + (tj + 16*m)*260 + k4);
#pragma unroll
            for (int a = 0; a < 2; a++)
#pragma unroll
                for (int c2 = 0; c2 < 4; c2++) {
                    acc[a][c2].x += av[a].x * bv[c2].x;
                    acc[a][c2].y += av[a].y * bv[c2].y;
                    acc[a][c2].z += av[a].z * bv[c2].z;
                    acc[a][c2].w += av[a].w * bv[c2].w;
                }
        }
#pragma unroll
        for (int a = 0; a < 2; a++)
#pragma unroll
            for (int c2 = 0; c2 < 4; c2++) {
                int r = tr + 16*a, j = tj + 16*c2, i = 2*r + 1;
                float d = acc[a][c2].x + acc[a][c2].y + acc[a][c2].z + acc[a][c2].w;
                cMq[(cb*32 + r)*64 + j] = (j <= i) ? d * expf(gcl[i] - gcl[j]) : 0.f;
            }
    }
    if (tid < 32)                cMeta[cb*128 + tid] = Dl[2*tid + 1];
    if (tid >= 32 && tid < 96)   cMeta[cb*128 + tid] = expf(gcl[63] - gcl[tid - 32]);
    if (tid == 96)               cMeta[cb*128 + 96]  = Dl[63];
    __syncthreads();

    float* Xs = Cr;
    for (int i = 0; i < 64; i++) Xs[i*260 + tid] = bl[i] * Dl[i] * Kl[i*260 + tid];
    for (int i = 1; i < 64; i++) {
        float a2 = Xs[i*260 + tid];
        const float* arow = Al + i*65;
        for (int j = 0; j < i; j++) a2 -= arow[j] * Xs[j*260 + tid];
        Xs[i*260 + tid] = a2;
    }
    {
        float* Wg = cWm + cb * (size_t)(LE*CC);
        for (int i = 0; i < 64; i++) Wg[(size_t)i*CC + tid] = Xs[i*260 + tid];
    }
    for (int i = 0; i < 64; i++) Xs[i*260 + tid] = bl[i] * vg[(size_t)i*CC + tid];
    for (int i = 1; i < 64; i++) {
        float a2 = Xs[i*260 + tid];
        const float* arow = Al + i*65;
        for (int j = 0; j < i; j++) a2 -= arow[j] * Xs[j*260 + tid];
        Xs[i*260 + tid] = a2;
    }
    {
        float* Ug = cUl + cb * (size_t)(LE*CC);
        for (int i = 0; i < 64; i++) Ug[(size_t)i*CC + tid] = Xs[i*260 + tid];
    }
}

// ---------------------------------------------------------------------------
// chunk_mats: per (chunk-block cb, tile z) computes the affine operators:
//   A[d][k] = DL*I - (Kgs^T Wm)    stored A_v4[(cb*64+k>>2)*1024 + d*4 + (k&3)]
//   B[d][c] = (Kgs^T Ul)           stored B_t[cb*65536 + c*256 + d]
//   P[r][k] = Dodd[r]*Q[r][k] - (Mq Wm)  stored P_v4[(cb*64+k>>2)*128 + r*4 + (k&3)]
//   E[r][c] = (Mq Ul)              stored E_t[cb*8192 + c*32 + r]
// Kgs[j][d] = kn[j][d]*Ks[j].
// z: 0..15 A-tiles (64k x 64d), 16..31 B (64c x 64d), 32..35 P (64k x 32r),
//    36..39 E (64c x 32r).
// ---------------------------------------------------------------------------
__global__ __launch_bounds__(256) void chunk_mats(
    const float* __restrict__ qn, const float* __restrict__ kn,
    const float* __restrict__ cWm, const float* __restrict__ cUl,
    const float* __restrict__ cMq, const float* __restrict__ cMeta,
    float* __restrict__ A_g, float* __restrict__ B_t,
    float* __restrict__ P_g, float* __restrict__ E_t)
{
    __shared__ float a1[64*68];
    __shared__ float a2[64*68];
    const int tid = threadIdx.x;
    const int cb = blockIdx.x;        // b*NCH + ch
    const int z  = blockIdx.y;        // 0..39
    const int b  = cb >> 6;
    const int ch = cb & 63;

    const float* Wm = cWm + (size_t)cb * (LE*CC);
    const float* Ul = cUl + (size_t)cb * (LE*CC);
    const float* Kc = kn + ((size_t)b*TE + (size_t)ch*LE) * CC;
    const float* Mq = cMq + (size_t)cb * 2048;
    const float* Mt = cMeta + (size_t)cb * 128;

    const bool isA = (z < 16);
    const bool isB = (z >= 16 && z < 32);
    const bool isP = (z >= 32 && z < 36);

    const float* A1src; int mbase;
    if (isA)      { A1src = Wm; mbase = (z >> 2) * 64; }
    else if (isB) { A1src = Ul; mbase = ((z - 16) >> 2) * 64; }
    else if (isP) { A1src = Wm; mbase = (z - 32) * 64; }
    else          { A1src = Ul; mbase = (z - 36) * 64; }
    const int nbase = (z < 32) ? (z & 3) * 64 : 0;

    // stage a1: [j][64 m-cols]
    {
        const int j = tid >> 2, c16 = (tid & 3) * 16;
#pragma unroll
        for (int i = 0; i < 4; i++) {
            float4 v = *(const float4*)(A1src + (size_t)j*CC + mbase + c16 + 4*i);
            *(float4*)&a1[j*68 + c16 + 4*i] = v;
        }
    }
    // stage a2
    if (z < 32) {   // Kgs tile [j][64 d]
        const int j = tid >> 2, c16 = (tid & 3) * 16;
        const float ks = Mt[32 + j];
#pragma unroll
        for (int i = 0; i < 4; i++) {
            float4 v = *(const float4*)(Kc + (size_t)j*CC + nbase + c16 + 4*i);
            v.x *= ks; v.y *= ks; v.z *= ks; v.w *= ks;
            *(float4*)&a2[j*68 + c16 + 4*i] = v;
        }
    } else {        // Mq^T [j][32 r]
        const int r = tid >> 3, j8 = (tid & 7) * 8;
        float vv[8];
#pragma unroll
        for (int i = 0; i < 8; i++) vv[i] = Mq[r*64 + j8 + i];
#pragma unroll
        for (int i = 0; i < 8; i++) a2[(j8 + i)*68 + r] = vv[i];
    }
    __syncthreads();

    if (z < 32) {
        const int tm = tid >> 4, tn = tid & 15;
        float acc[4][4];
#pragma unroll
        for (int i = 0; i < 4; i++)
#pragma unroll
            for (int j2 = 0; j2 < 4; j2++) acc[i][j2] = 0.f;
        for (int j = 0; j < 64; j++) {
            float4 x = *(const float4*)&a1[j*68 + 4*tm];
            float4 y = *(const float4*)&a2[j*68 + 4*tn];
            float xs[4] = {x.x, x.y, x.z, x.w};
            float ys[4] = {y.x, y.y, y.z, y.w};
#pragma unroll
            for (int i = 0; i < 4; i++)
#pragma unroll
                for (int j2 = 0; j2 < 4; j2++) acc[i][j2] += xs[i] * ys[j2];
        }
        if (isA) {
            const float DL = Mt[96];
#pragma unroll
            for (int mi = 0; mi < 4; mi++)
#pragma unroll
                for (int ni = 0; ni < 4; ni++) {
                    const int k = mbase + 4*tm + mi, d = nbase + 4*tn + ni;
                    float val = -acc[mi][ni] + ((k == d) ? DL : 0.f);
                    A_g[((size_t)cb*64 + (k >> 2))*1024 + d*4 + (k & 3)] = val;
                }
        } else {
#pragma unroll
            for (int mi = 0; mi < 4; mi++) {
                const int c = mbase + 4*tm + mi, d0 = nbase + 4*tn;
                float4 o = make_float4(acc[mi][0], acc[mi][1], acc[mi][2], acc[mi][3]);
                *(float4*)&B_t[(size_t)cb*65536 + (size_t)c*256 + d0] = o;
            }
        }
    } else if (tid < 128) {
        const int tm = tid >> 3, tn = tid & 7;   // 16 m-quads x 8 r-quads
        float acc[4][4];
#pragma unroll
        for (int i = 0; i < 4; i++)
#pragma unroll
            for (int j2 = 0; j2 < 4; j2++) acc[i][j2] = 0.f;
        for (int j = 0; j < 64; j++) {
            float4 x = *(const float4*)&a1[j*68 + 4*tm];
            float4 y = *(const float4*)&a2[j*68 + 4*tn];
            float xs[4] = {x.x, x.y, x.z, x.w};
            float ys[4] = {y.x, y.y, y.z, y.w};
#pragma unroll
            for (int i = 0; i < 4; i++)
#pragma unroll
                for (int j2 = 0; j2 < 4; j2++) acc[i][j2] += xs[i] * ys[j2];
        }
        if (isP) {
#pragma unroll
            for (int mi = 0; mi < 4; mi++)
#pragma unroll
                for (int ni = 0; ni < 4; ni++) {
                    const int k = mbase + 4*tm + mi, r = 4*tn + ni;
                    const float dq = Mt[r] * qn[((size_t)b*TT + (size_t)ch*LT + r)*CC + k];
                    P_g[((size_t)cb*64 + (k >> 2))*128 + r*4 + (k & 3)] = dq - acc[mi][ni];
                }
        } else {
#pragma unroll
            for (int mi = 0; mi < 4; mi++) {
                const int c = mbase + 4*tm + mi, r0 = 4*tn;
                float4 o = make_float4(acc[mi][0], acc[mi][1], acc[mi][2], acc[mi][3]);
                *(float4*)&E_t[(size_t)cb*8192 + (size_t)c*32 + r0] = o;
            }
        }
    }
}

// ---------------------------------------------------------------------------
// chain2: sequential over chunks. Per block: 4 state columns. S in LDS (4KB
// double buffer); A/P streamed from global (coalesced dwordx4); 1 barrier per
// chunk. S' = A*S + B ; O = P*S + E.
// ---------------------------------------------------------------------------
__global__ __launch_bounds__(256, 1) void chain2(
    const float* __restrict__ A_g, const float* __restrict__ B_t,
    const float* __restrict__ P_g, const float* __restrict__ E_t,
    float* __restrict__ o_mid)
{
    __shared__ float S2[2][1024];   // [buf][k*4 + c]
    const int tid = threadIdx.x;
    const int b = blockIdx.y;
    const int col0 = blockIdx.x * 4;
    const int r = tid & 31;          // P/O row
    const int h = (tid >> 5) & 1;    // k-half for P
    const int w = tid >> 6;          // wave = output column

    *(float4*)&S2[0][tid*4] = make_float4(0.f, 0.f, 0.f, 0.f);
    __syncthreads();

    for (int ch = 0; ch < NCH; ch++) {
        const int cur = ch & 1, nxt = cur ^ 1;
        const size_t cb = (size_t)b * NCH + ch;
        const float* Ab = A_g + cb*65536 + (size_t)tid*4;
        const float* Pb = P_g + cb*8192 + (size_t)r*4;

        float ax = B_t[cb*65536 + (size_t)(col0 + 0)*256 + tid];
        float ay = B_t[cb*65536 + (size_t)(col0 + 1)*256 + tid];
        float az = B_t[cb*65536 + (size_t)(col0 + 2)*256 + tid];
        float aw = B_t[cb*65536 + (size_t)(col0 + 3)*256 + tid];
        float pacc = 0.f;

#pragma unroll
        for (int kt = 0; kt < 8; kt++) {
            float4 Av[8];
#pragma unroll
            for (int u = 0; u < 8; u++)
                Av[u] = *(const float4*)(Ab + (size_t)(kt*8 + u)*1024);
            const bool ph = ((kt >> 2) == h);
            float4 Pv[8];
            if (ph) {
#pragma unroll
                for (int u = 0; u < 8; u++)
                    Pv[u] = *(const float4*)(Pb + (size_t)(kt*8 + u)*128);
            }
#pragma unroll
            for (int u = 0; u < 8; u++) {
                const int k0 = (kt*8 + u)*4;
                float4 s0 = *(const float4*)&S2[cur][(k0 + 0)*4];
                float4 s1 = *(const float4*)&S2[cur][(k0 + 1)*4];
                float4 s2 = *(const float4*)&S2[cur][(k0 + 2)*4];
                float4 s3 = *(const float4*)&S2[cur][(k0 + 3)*4];
                ax += Av[u].x*s0.x + Av[u].y*s1.x + Av[u].z*s2.x + Av[u].w*s3.x;
                ay += Av[u].x*s0.y + Av[u].y*s1.y + Av[u].z*s2.y + Av[u].w*s3.y;
                az += Av[u].x*s0.z + Av[u].y*s1.z + Av[u].z*s2.z + Av[u].w*s3.z;
                aw += Av[u].x*s0.w + Av[u].y*s1.w + Av[u].z*s2.w + Av[u].w*s3.w;
                if (ph) {
                    float sw0 = S2[cur][(k0 + 0)*4 + w];
                    float sw1 = S2[cur][(k0 + 1)*4 + w];
                    float sw2 = S2[cur][(k0 + 2)*4 + w];
                    float sw3 = S2[cur][(k0 + 3)*4 + w];
                    pacc += Pv[u].x*sw0 + Pv[u].y*sw1 + Pv[u].z*sw2 + Pv[u].w*sw3;
                }
            }
        }

        pacc += __shfl_xor(pacc, 32, 64);
        *(float4*)&S2[nxt][tid*4] = make_float4(ax, ay, az, aw);
        if (h == 0) {
            const float e = E_t[cb*8192 + (size_t)(col0 + w)*32 + r];
            o_mid[((size_t)b*TT + (size_t)ch*LT + r)*CC + col0 + w] = pacc + e;
        }
        __syncthreads();
    }
}

// ---------------------------------------------------------------------------
// o = o * rsqrt(mean(o^2) + 1e-5) * o_norm_w * silu(gate)
// ---------------------------------------------------------------------------
__global__ __launch_bounds__(256) void norm_gate(
    const float* __restrict__ o_mid, float* __restrict__ gate,
    const float* __restrict__ onw)
{
    const int bt = blockIdx.x;
    const int c  = threadIdx.x;
    const float o = o_mid[(size_t)bt * CC + c];
    float ss = o * o;
#pragma unroll
    for (int m = 1; m < 64; m <<= 1) ss += __shfl_xor(ss, m, 64);
    __shared__ float red[4];
    if ((c & 63) == 0) red[c >> 6] = ss;
    __syncthreads();
    const float mean = (red[0] + red[1] + red[2] + red[3]) * (1.f / 256.f);
    const float scale = rsqrtf(mean + 1e-5f);
    const float gv = gate[(size_t)bt * CC + c];
    const float silu = gv / (1.f + expf(-gv));
    gate[(size_t)bt * CC + c] = o * scale * onw[c] * silu;
}

// ---------------------------------------------------------------------------
extern "C" void kernel_launch(void* const* d_in, const int* in_sizes, int n_in,
                              void* d_out, int out_size, void* d_ws, size_t ws_size,
                              hipStream_t stream)
{
    const float* x        = (const float*)d_in[0];
    const float* Wq       = (const float*)d_in[1];
    const float* Wk       = (const float*)d_in[2];
    const float* Wv       = (const float*)d_in[3];
    const float* Wb       = (const float*)d_in[4];
    const float* Wa       = (const float*)d_in[5];
    const float* A_log    = (const float*)d_in[6];
    const float* dt_bias  = (const float*)d_in[7];
    const float* q_conv_w = (const float*)d_in[8];
    const float* k_conv_w = (const float*)d_in[9];
    const float* v_conv_w = (const float*)d_in[10];
    const float* Wg       = (const float*)d_in[11];
    const float* o_norm_w = (const float*)d_in[12];
    const float* Wo       = (const float*)d_in[13];
    float* out = (float*)d_out;

    float* ws = (float*)d_ws;
    // A_g (8*BTC floats) overlays q_pre/k_pre/v_pre (dead after conv_silu).
    float* A_g    = ws;                    // 8*BTC (spans [0, 8*BTC))
    float* q_pre  = ws;                    // 1*BTC   (conv input; dead pre-chunk_mats)
    float* k_pre  = ws + 1 * BTC;          // 2*BTC
    float* v_pre  = ws + 3 * BTC;          // 2*BTC
    float* gate   = ws + 8 * BTC;          // 1
    float* qn     = ws + 9 * BTC;          // 1
    float* kn     = ws + 10 * BTC;         // 2
    float* vn     = ws + 12 * BTC;         // 2
    float* o_mid  = ws + 14 * BTC;         // 1
    float* g_arr  = ws + 15 * BTC;         // BT
    float* beta_a = g_arr + BT;            // 2*BT
    float* cWm    = beta_a + 2 * (size_t)BT;   // 2*BTC
    float* cUl    = cWm + 2 * BTC;             // 2*BTC
    float* cMq    = cUl + 2 * BTC;             // NCB*2048
    float* cMeta  = cMq + (size_t)NCB * 2048;  // NCB*128
    float* B_t    = cMeta + (size_t)NCB * 128; // 8*BTC
    float* P_g    = B_t + 8 * BTC;             // 1*BTC
    float* E_t    = P_g + 1 * BTC;             // 1*BTC

    const int PRE_LDS = 37632 * 4;   // 150528 B
    hipFuncSetAttribute(reinterpret_cast<const void*>(chunk_pre),
                        hipFuncAttributeMaxDynamicSharedMemorySize, PRE_LDS);

    const dim3 gg(BT / 64, CC / 64), gb(256);
    GemmBatch gbatch;
    gbatch.B[0] = Wq;           gbatch.C[0] = q_pre;
    gbatch.B[1] = Wk;           gbatch.C[1] = k_pre;
    gbatch.B[2] = Wk + CC*CC;   gbatch.C[2] = k_pre + BTC;
    gbatch.B[3] = Wv;           gbatch.C[3] = v_pre;
    gbatch.B[4] = Wv + CC*CC;   gbatch.C[4] = v_pre + BTC;
    gbatch.B[5] = Wg;           gbatch.C[5] = gate;
    gemm_f32_batch<<<dim3(BT/64, CC/64, 6), gb, 0, stream>>>(x, gbatch, BT, CC, CC);
    proj_scalars<<<BT, 64, 0, stream>>>(x, Wb, Wa, A_log, dt_bias, g_arr, beta_a);
    conv_silu<<<dim3(BT, 5), 256, 0, stream>>>(q_pre, k_pre, v_pre,
                                               q_conv_w, k_conv_w, v_conv_w,
                                               qn, kn, vn);
    chunk_pre<<<dim3(NCH, BB), 256, PRE_LDS, stream>>>(qn, kn, vn, g_arr, beta_a,
                                                       cWm, cUl, cMq, cMeta);
    chunk_mats<<<dim3(NCB, 40), 256, 0, stream>>>(qn, kn, cWm, cUl, cMq, cMeta,
                                                  A_g, B_t, P_g, E_t);
    chain2<<<dim3(CC/4, BB), 256, 0, stream>>>(A_g, B_t, P_g, E_t, o_mid);
    norm_gate<<<BT, 256, 0, stream>>>(o_mid, gate, o_norm_w);
    gemm_f32<<<gg, gb, 0, stream>>>(gate, Wo, out, BT, CC, CC);
}